// Round 5
// baseline (489.046 us; speedup 1.0000x reference)
//
#include <hip/hip_runtime.h>
#include <hip/hip_bf16.h>
#include <cstdint>
#include <cstddef>

#define B_   8192
#define D_   2048
#define H1_  1024
#define H2_  512
#define G_   512
#define T_   2
#define E_   6
#define EC_  4

typedef __bf16 bf16_t;
typedef __attribute__((ext_vector_type(8))) __bf16 bf16x8;
typedef __attribute__((ext_vector_type(4))) float f32x4;

// ---------------------------------------------------------------------------
// async global->LDS, 16B per lane. LDS dest is wave-uniform base + lane*16.
// ---------------------------------------------------------------------------
__device__ __forceinline__ void gload_lds16(const bf16_t* g, bf16_t* l) {
    __builtin_amdgcn_global_load_lds(
        (const __attribute__((address_space(1))) bf16_t*)g,
        (__attribute__((address_space(3))) bf16_t*)l,
        16, 0, 0);
}

// ---------------------------------------------------------------------------
// cast x (fp32) -> bf16, 8 elems/thread
// ---------------------------------------------------------------------------
__global__ __launch_bounds__(256) void cast_x_kernel(
    const float* __restrict__ src, bf16_t* __restrict__ dst, int n8)
{
    int i = blockIdx.x * blockDim.x + threadIdx.x;
    if (i >= n8) return;
    const float4* s = (const float4*)src + (size_t)i * 2;
    float4 a = s[0], b = s[1];
    bf16x8 o;
    o[0] = (bf16_t)a.x; o[1] = (bf16_t)a.y; o[2] = (bf16_t)a.z; o[3] = (bf16_t)a.w;
    o[4] = (bf16_t)b.x; o[5] = (bf16_t)b.y; o[6] = (bf16_t)b.z; o[7] = (bf16_t)b.w;
    *(bf16x8*)(dst + (size_t)i * 8) = o;
}

// ---------------------------------------------------------------------------
// transpose + cast: src (batch, R, C) fp32 -> dst (batch, C, R) bf16
// ---------------------------------------------------------------------------
__global__ __launch_bounds__(256) void transpose_cast_kernel(
    const float* __restrict__ src, bf16_t* __restrict__ dst, int R, int C)
{
    __shared__ float tile[32][33];
    int bz = blockIdx.z;
    src += (size_t)bz * R * C;
    dst += (size_t)bz * R * C;
    int c0 = blockIdx.x * 32, r0 = blockIdx.y * 32;
    int tx = threadIdx.x, ty = threadIdx.y;
#pragma unroll
    for (int i = 0; i < 32; i += 8)
        tile[ty + i][tx] = src[(size_t)(r0 + ty + i) * C + (c0 + tx)];
    __syncthreads();
#pragma unroll
    for (int i = 0; i < 32; i += 8)
        dst[(size_t)(c0 + ty + i) * R + (r0 + tx)] = (bf16_t)tile[tx][ty + i];
}

// ---------------------------------------------------------------------------
// 256x256-tile GEMM, single-barrier reg-dbuf pipeline:
//   C = relu(A(M,K)*Bt(N,K)^T + bias), bf16 in/out, fp32 MFMA accumulate.
// 8 waves (2M x 4N), per-wave 128x64 (acc = 128 AGPR), BK=32.
// 4 LDS buffers (128 KB), 1 block/CU, 2 waves/SIMD.
// iter t: STAGE(t+4)->buf[t&3] || ds_read frags(t+1) || MFMA(t) on regset t&1,
//         then s_waitcnt vmcnt(8) lgkmcnt(0), ONE barrier.
// vmcnt(8) leaves tiles t+3,t+4 in flight (never drains to 0 mid-loop);
// guarantees t+2 done (consumed by next iter's reads). Buffer overwrite safe:
// frags(t) were read in iter t-1, proven by its lgkm(0)+barrier.
// XOR swizzle chunk ^= (row>>1)&3 (16B chunks) on BOTH stage-source and
// ds_read (rule 21); measured conflict-free in rounds 2-4.
// Requires: M%256==0, N%256==0, K%128==0, gridX*gridY%8==0.
// ---------------------------------------------------------------------------
template<int K>
__global__ __launch_bounds__(512, 2) void gemm256_tpl(
    const bf16_t* __restrict__ A, const bf16_t* __restrict__ Bt,
    const float* __restrict__ bias, bf16_t* __restrict__ C,
    int M, int N, long long strideA)
{
    constexpr int NT   = K / 32;      // K-tiles
    constexpr int MAIN = NT - 4;      // staged iterations (multiple of 4)
    static_assert(K % 128 == 0, "NT must be multiple of 4");

    const int e = blockIdx.z;
    A    += (size_t)e * (size_t)strideA;
    Bt   += (size_t)e * (size_t)N * (size_t)K;
    bias += (size_t)e * (size_t)N;
    C    += (size_t)e * (size_t)M * (size_t)N;

    // T1: XCD swizzle within this z-slice (nwg % 8 == 0 by launch contract)
    const int gx  = gridDim.x;
    const int nwg = gx * gridDim.y;
    const int lin = blockIdx.y * gx + blockIdx.x;
    const int swz = (lin & 7) * (nwg >> 3) + (lin >> 3);
    const int row0 = (swz / gx) * 256;
    const int col0 = (swz % gx) * 256;

    __shared__ bf16_t lsA[4][8192];   // 4 buffers x 256 rows x 32 (16 KB each)
    __shared__ bf16_t lsB[4][8192];   // total 128 KB

    const int tid  = threadIdx.x;
    const int lane = tid & 63;
    const int wave = tid >> 6;        // 0..7
    const int wr   = wave >> 2;       // 0..1 : 128-row half
    const int wc   = wave & 3;        // 0..3 : 64-col quarter

    // ---- staging: tile 256x32, slots = l*512+tid, 2 loads per matrix -------
    // slot -> row = slot>>2, phys chunk = slot&3, logical c = pc ^ ((row>>1)&3)
    size_t offs[2];
#pragma unroll
    for (int l = 0; l < 2; ++l) {
        int idx = l * 512 + tid;
        int r   = idx >> 2;
        int c   = (idx & 3) ^ ((r >> 1) & 3);
        offs[l] = (size_t)r * (size_t)K + (size_t)(c * 8);
    }
    const int ldsOff0 = wave * 512;           // elements, wave-uniform
    const int ldsOff1 = 4096 + wave * 512;

    const bf16_t* pA0 = A  + (size_t)row0 * (size_t)K + offs[0];
    const bf16_t* pA1 = A  + (size_t)row0 * (size_t)K + offs[1];
    const bf16_t* pB0 = Bt + (size_t)col0 * (size_t)K + offs[0];
    const bf16_t* pB1 = Bt + (size_t)col0 * (size_t)K + offs[1];

    // ---- fragment read addressing (elements), same XOR involution ----------
    const int xch  = ((lane >> 4) ^ ((lane >> 1) & 3)) << 3;
    const int aoff = (wr * 128 + (lane & 15)) * 32 + xch;
    const int boff = (wc * 64  + (lane & 15)) * 32 + xch;

    f32x4 acc[8][4];
#pragma unroll
    for (int m = 0; m < 8; ++m)
#pragma unroll
        for (int n = 0; n < 4; ++n)
            acc[m][n] = (f32x4){0.f, 0.f, 0.f, 0.f};

    bf16x8 aF0[8], bF0[4], aF1[8], bF1[4];

#define STAGE(kt_, bi_) do {                                                  \
    gload_lds16(pA0 + (size_t)(kt_) * 32, &lsA[bi_][ldsOff0]);                \
    gload_lds16(pA1 + (size_t)(kt_) * 32, &lsA[bi_][ldsOff1]);                \
    gload_lds16(pB0 + (size_t)(kt_) * 32, &lsB[bi_][ldsOff0]);                \
    gload_lds16(pB1 + (size_t)(kt_) * 32, &lsB[bi_][ldsOff1]);                \
} while (0)

#define RD(nx_, bi_) do {                                                     \
    _Pragma("unroll")                                                         \
    for (int m_ = 0; m_ < 8; ++m_)                                            \
        aF##nx_[m_] = *(const bf16x8*)&lsA[bi_][aoff + m_ * 512];             \
    _Pragma("unroll")                                                         \
    for (int n_ = 0; n_ < 4; ++n_)                                            \
        bF##nx_[n_] = *(const bf16x8*)&lsB[bi_][boff + n_ * 512];             \
} while (0)

#define MM(cu_) do {                                                          \
    __builtin_amdgcn_s_setprio(1);                                            \
    _Pragma("unroll")                                                         \
    for (int m_ = 0; m_ < 8; ++m_)                                            \
        _Pragma("unroll")                                                     \
        for (int n_ = 0; n_ < 4; ++n_)                                        \
            acc[m_][n_] = __builtin_amdgcn_mfma_f32_16x16x32_bf16(            \
                aF##cu_[m_], bF##cu_[n_], acc[m_][n_], 0, 0, 0);              \
    __builtin_amdgcn_s_setprio(0);                                            \
} while (0)

#define ENDI(vm_) do {                                                        \
    asm volatile("s_waitcnt vmcnt(" #vm_ ") lgkmcnt(0)" ::: "memory");        \
    __builtin_amdgcn_sched_barrier(0);                                        \
    __builtin_amdgcn_s_barrier();                                             \
    __builtin_amdgcn_sched_barrier(0);                                        \
} while (0)

    // ---- prologue: stage tiles 0..3; tiles 0,1 complete; frags(0) -> set0 --
    STAGE(0, 0); STAGE(1, 1); STAGE(2, 2); STAGE(3, 3);
    asm volatile("s_waitcnt vmcnt(8)" ::: "memory");   // tiles 0,1 done
    __builtin_amdgcn_sched_barrier(0);
    __builtin_amdgcn_s_barrier();
    __builtin_amdgcn_sched_barrier(0);
    RD(0, 0);
    asm volatile("s_waitcnt lgkmcnt(0)" ::: "memory");
    __builtin_amdgcn_sched_barrier(0);
    __builtin_amdgcn_s_barrier();
    __builtin_amdgcn_sched_barrier(0);

    // ---- main loop: 4 iters per group, all buffer/regset indices static ----
    for (int tb = 0; tb < MAIN; tb += 4) {
        STAGE(tb + 4, 0); RD(1, 1); MM(0); ENDI(8);
        STAGE(tb + 5, 1); RD(0, 2); MM(1); ENDI(8);
        STAGE(tb + 6, 2); RD(1, 3); MM(0); ENDI(8);
        STAGE(tb + 7, 3); RD(0, 0); MM(1); ENDI(8);
    }

    // ---- tail: tiles NT-4..NT-1, no staging, drain 4 -> 0 ------------------
    RD(1, 1); MM(0); ENDI(4);
    RD(0, 2); MM(1); ENDI(0);
    RD(1, 3); MM(0);
    asm volatile("s_waitcnt lgkmcnt(0)" ::: "memory");
    __builtin_amdgcn_sched_barrier(0);
    MM(1);

#undef STAGE
#undef RD
#undef MM
#undef ENDI

    // ---- epilogue: C/D layout col = lane&15, row = (lane>>4)*4 + j ----------
    const int crb = row0 + wr * 128 + ((lane >> 4) << 2);
    const int ccb = col0 + wc * 64  + (lane & 15);
#pragma unroll
    for (int n = 0; n < 4; ++n) {
        const int cc = ccb + n * 16;
        const float bv = bias[cc];
#pragma unroll
        for (int m = 0; m < 8; ++m) {
            const int rb = crb + m * 16;
#pragma unroll
            for (int j = 0; j < 4; ++j) {
                float v = acc[m][n][j] + bv;
                v = v > 0.f ? v : 0.f;
                C[(size_t)(rb + j) * N + cc] = (bf16_t)v;
            }
        }
    }
}

// ---------------------------------------------------------------------------
// gate: logits[t,b,e] = sum_g g[t,b,g] * Wgs[t,g,e]; softmax over e (EC=4).
// g lives in h1 slice 6: row (t,b) at h1[(6*B + b)*1024 + t*512 ..].
// ---------------------------------------------------------------------------
__global__ __launch_bounds__(256) void gate_kernel(
    const bf16_t* __restrict__ h1, const float* __restrict__ Wgs,
    float* __restrict__ gate)
{
    int wid  = blockIdx.x * 4 + (threadIdx.x >> 6);   // t*B + b
    int lane = threadIdx.x & 63;
    int t = wid >> 13;                                // B_ = 8192
    int b = wid & (B_ - 1);
    const bf16_t* grow = h1 + ((size_t)(6 * B_) + b) * 1024 + t * G_;
    bf16x8 gv = *(const bf16x8*)&grow[lane * 8];
    const float* W = Wgs + (size_t)t * G_ * EC_;
    float a0 = 0.f, a1 = 0.f, a2 = 0.f, a3 = 0.f;
#pragma unroll
    for (int i = 0; i < 8; ++i) {
        float gvf = (float)gv[i];
        const float4 w = *(const float4*)&W[(size_t)(lane * 8 + i) * 4];
        a0 += gvf * w.x; a1 += gvf * w.y; a2 += gvf * w.z; a3 += gvf * w.w;
    }
#pragma unroll
    for (int off = 32; off; off >>= 1) {
        a0 += __shfl_xor(a0, off);
        a1 += __shfl_xor(a1, off);
        a2 += __shfl_xor(a2, off);
        a3 += __shfl_xor(a3, off);
    }
    if (lane == 0) {
        float m  = fmaxf(fmaxf(a0, a1), fmaxf(a2, a3));
        float e0 = expf(a0 - m), e1 = expf(a1 - m), e2 = expf(a2 - m), e3 = expf(a3 - m);
        float inv = 1.f / (e0 + e1 + e2 + e3);
        *(float4*)&gate[(size_t)wid * 4] = make_float4(e0 * inv, e1 * inv, e2 * inv, e3 * inv);
    }
}

// ---------------------------------------------------------------------------
// combine: out[t,b,o] = sum_j gate[t,b,j] * h2[IDX[t][j], b, o]
// ---------------------------------------------------------------------------
__global__ __launch_bounds__(256) void combine_kernel(
    const bf16_t* __restrict__ h2, const float* __restrict__ gate,
    float* __restrict__ out)
{
    size_t idx = (size_t)blockIdx.x * 256 + threadIdx.x;
    size_t tb  = idx >> 6;
    int    o0  = (int)(idx & 63) * 8;
    int    t   = (int)(tb >> 13);
    size_t b   = tb & (size_t)(B_ - 1);
    const float4 gv = *(const float4*)&gate[tb * 4];
    const bf16x8 v0 = *(const bf16x8*)&h2[((size_t)(2 * t)     * B_ + b) * H2_ + o0];
    const bf16x8 v1 = *(const bf16x8*)&h2[((size_t)(2 * t + 1) * B_ + b) * H2_ + o0];
    const bf16x8 v2 = *(const bf16x8*)&h2[((size_t)4           * B_ + b) * H2_ + o0];
    const bf16x8 v3 = *(const bf16x8*)&h2[((size_t)5           * B_ + b) * H2_ + o0];
    float r[8];
#pragma unroll
    for (int i = 0; i < 8; ++i)
        r[i] = gv.x * (float)v0[i] + gv.y * (float)v1[i]
             + gv.z * (float)v2[i] + gv.w * (float)v3[i];
    float4* op = (float4*)&out[tb * H2_ + o0];
    op[0] = make_float4(r[0], r[1], r[2], r[3]);
    op[1] = make_float4(r[4], r[5], r[6], r[7]);
}

// ---------------------------------------------------------------------------
extern "C" void kernel_launch(void* const* d_in, const int* in_sizes, int n_in,
                              void* d_out, int out_size, void* d_ws, size_t ws_size,
                              hipStream_t stream)
{
    const float* x   = (const float*)d_in[0];
    const float* We1 = (const float*)d_in[1];
    const float* be1 = (const float*)d_in[2];
    const float* We2 = (const float*)d_in[3];
    const float* be2 = (const float*)d_in[4];
    const float* Wg1 = (const float*)d_in[5];
    const float* bg1 = (const float*)d_in[6];
    const float* Wgs = (const float*)d_in[7];
    float* out = (float*)d_out;

    char* ws = (char*)d_ws;
    bf16_t* x_bf  = (bf16_t*)ws;  ws += (size_t)B_ * D_ * 2;             //  33.6 MB
    bf16_t* w1t   = (bf16_t*)ws;  ws += (size_t)7 * H1_ * D_ * 2;        //  29.4 MB (6 experts + gate)
    bf16_t* w2t   = (bf16_t*)ws;  ws += (size_t)E_ * H2_ * H1_ * 2;      //   6.3 MB
    bf16_t* h1    = (bf16_t*)ws;  ws += (size_t)7 * B_ * H1_ * 2;        // 117.4 MB (slice 6 = gate g)
    bf16_t* h2    = (bf16_t*)ws;  ws += (size_t)E_ * B_ * H2_ * 2;       //  50.3 MB
    float*  bias7 = (float*)ws;   ws += (size_t)7 * H1_ * 4;             //  28 KB
    float*  gate  = (float*)ws;   ws += (size_t)T_ * B_ * EC_ * 4;       //   0.3 MB

    bf16_t* wgt = w1t + (size_t)6 * H1_ * D_;   // gate weights = expert slice 6

    // 0) bias concat (d2d async, graph-capture safe)
    hipMemcpyAsync(bias7, be1, (size_t)E_ * H1_ * sizeof(float),
                   hipMemcpyDeviceToDevice, stream);
    hipMemcpyAsync(bias7 + (size_t)E_ * H1_, bg1, (size_t)T_ * G_ * sizeof(float),
                   hipMemcpyDeviceToDevice, stream);

    // 1) casts / transposes
    cast_x_kernel<<<(B_ * D_ / 8) / 256, 256, 0, stream>>>(x, x_bf, B_ * D_ / 8);
    dim3 tb(32, 8);
    transpose_cast_kernel<<<dim3(H1_ / 32, D_ / 32, E_),  tb, 0, stream>>>(We1, w1t, D_,  H1_);
    transpose_cast_kernel<<<dim3(H2_ / 32, H1_ / 32, E_), tb, 0, stream>>>(We2, w2t, H1_, H2_);
    transpose_cast_kernel<<<dim3(G_ / 32, D_ / 32, T_),   tb, 0, stream>>>(Wg1, wgt, D_,  G_);

    // 2) GEMM1 + gate folded: z = 0..5 experts, z = 6 gate (N=1024 each)
    gemm256_tpl<2048><<<dim3(H1_ / 256, B_ / 256, 7), 512, 0, stream>>>(
        x_bf, w1t, bias7, h1, B_, H1_, 0LL);
    // 3) GEMM2 over experts 0..5
    gemm256_tpl<1024><<<dim3(H2_ / 256, B_ / 256, E_), 512, 0, stream>>>(
        h1, w2t, be2, h2, B_, H2_, (long long)B_ * H1_);

    // 4) gate softmax + final combine
    gate_kernel<<<(T_ * B_) / 4, 256, 0, stream>>>(h1, Wgs, gate);
    combine_kernel<<<((size_t)T_ * B_ * H2_ / 8) / 256, 256, 0, stream>>>(h2, gate, out);
}

// Round 6
// 426.128 us; speedup vs baseline: 1.1476x; 1.1476x over previous
//
#include <hip/hip_runtime.h>
#include <hip/hip_bf16.h>
#include <cstdint>
#include <cstddef>

#define B_   8192
#define D_   2048
#define H1_  1024
#define H2_  512
#define G_   512
#define T_   2
#define E_   6
#define EC_  4

typedef __bf16 bf16_t;
typedef __attribute__((ext_vector_type(8))) __bf16 bf16x8;
typedef __attribute__((ext_vector_type(4))) float f32x4;

// ---------------------------------------------------------------------------
// async global->LDS, 16B per lane. LDS dest is wave-uniform base + lane*16.
// ---------------------------------------------------------------------------
__device__ __forceinline__ void gload_lds16(const bf16_t* g, bf16_t* l) {
    __builtin_amdgcn_global_load_lds(
        (const __attribute__((address_space(1))) bf16_t*)g,
        (__attribute__((address_space(3))) bf16_t*)l,
        16, 0, 0);
}

// ---------------------------------------------------------------------------
// cast x (fp32) -> bf16, 8 elems/thread
// ---------------------------------------------------------------------------
__global__ __launch_bounds__(256) void cast_x_kernel(
    const float* __restrict__ src, bf16_t* __restrict__ dst, int n8)
{
    int i = blockIdx.x * blockDim.x + threadIdx.x;
    if (i >= n8) return;
    const float4* s = (const float4*)src + (size_t)i * 2;
    float4 a = s[0], b = s[1];
    bf16x8 o;
    o[0] = (bf16_t)a.x; o[1] = (bf16_t)a.y; o[2] = (bf16_t)a.z; o[3] = (bf16_t)a.w;
    o[4] = (bf16_t)b.x; o[5] = (bf16_t)b.y; o[6] = (bf16_t)b.z; o[7] = (bf16_t)b.w;
    *(bf16x8*)(dst + (size_t)i * 8) = o;
}

// ---------------------------------------------------------------------------
// transpose + cast: src (batch, R, C) fp32 -> dst (batch, C, R) bf16
// ---------------------------------------------------------------------------
__global__ __launch_bounds__(256) void transpose_cast_kernel(
    const float* __restrict__ src, bf16_t* __restrict__ dst, int R, int C)
{
    __shared__ float tile[32][33];
    int bz = blockIdx.z;
    src += (size_t)bz * R * C;
    dst += (size_t)bz * R * C;
    int c0 = blockIdx.x * 32, r0 = blockIdx.y * 32;
    int tx = threadIdx.x, ty = threadIdx.y;
#pragma unroll
    for (int i = 0; i < 32; i += 8)
        tile[ty + i][tx] = src[(size_t)(r0 + ty + i) * C + (c0 + tx)];
    __syncthreads();
#pragma unroll
    for (int i = 0; i < 32; i += 8)
        dst[(size_t)(c0 + ty + i) * R + (r0 + tx)] = (bf16_t)tile[tx][ty + i];
}

// ---------------------------------------------------------------------------
// 256x256-tile GEMM, r4 schedule + r5 geometry (round 6):
//   C = relu(A(M,K)*Bt(N,K)^T + bias), bf16 in/out, fp32 MFMA accumulate.
// 8 waves (2M x 4N), per-wave 128x64 (acc = 128 AGPR, frags 48 VGPR, single
// set -> no spill). BK=32, 3 LDS buffers (96 KB), 1 block/CU, 2 waves/SIMD.
// LDS traffic 22.9 B/MFLOP (vs 30.5 for 64x64-wave geometry).
// iter t: RD frags(buf c) -> lgkm(0) -> barrier -> STAGE(t+3 -> c) ->
//         MFMA 8x4 -> counted vmcnt(8) -> barrier.  (r4-proven hazard logic;
// vmcnt(8) leaves tiles t+2,t+3 in flight, guarantees t+1 staged.)
// XOR swizzle chunk ^= (row>>1)&3 (16B chunks) on BOTH stage-source and
// ds_read (rule 21); conflict-free measured r2-r5; addressing r5-verified.
// Requires: M%256==0, N%256==0, K%32==0, K/32>=4, gridX*gridY%8==0.
// ---------------------------------------------------------------------------
__global__ __launch_bounds__(512, 2) void gemm256_s_kernel(
    const bf16_t* __restrict__ A, const bf16_t* __restrict__ Bt,
    const float* __restrict__ bias, bf16_t* __restrict__ C,
    int M, int N, int K, long long strideA)
{
    const int e = blockIdx.z;
    A    += (size_t)e * (size_t)strideA;
    Bt   += (size_t)e * (size_t)N * (size_t)K;
    bias += (size_t)e * (size_t)N;
    C    += (size_t)e * (size_t)M * (size_t)N;

    // T1: XCD swizzle within this z-slice (nwg % 8 == 0 by launch contract)
    const int gx  = gridDim.x;
    const int nwg = gx * gridDim.y;
    const int lin = blockIdx.y * gx + blockIdx.x;
    const int swz = (lin & 7) * (nwg >> 3) + (lin >> 3);
    const int row0 = (swz / gx) * 256;
    const int col0 = (swz % gx) * 256;

    __shared__ bf16_t lsA[3][8192];   // 3 x 16 KB (256 rows x 32)
    __shared__ bf16_t lsB[3][8192];   // 3 x 16 KB  -> 96 KB total

    const int tid  = threadIdx.x;
    const int lane = tid & 63;
    const int wave = tid >> 6;        // 0..7
    const int wr   = wave >> 2;       // 0..1 : 128-row half
    const int wc   = wave & 3;        // 0..3 : 64-col quarter

    // ---- staging: tile 256x32 = 1024 chunks(16B), slots l*512+tid ----------
    // slot -> row = slot>>2, phys chunk = slot&3, logical c = pc ^ ((row>>1)&3)
    size_t offs[2];
#pragma unroll
    for (int l = 0; l < 2; ++l) {
        int idx = l * 512 + tid;
        int r   = idx >> 2;
        int c   = (idx & 3) ^ ((r >> 1) & 3);
        offs[l] = (size_t)r * (size_t)K + (size_t)(c * 8);
    }
    const int ldsOff0 = wave * 512;           // elements, wave-uniform
    const int ldsOff1 = 4096 + wave * 512;

    const bf16_t* pA0 = A  + (size_t)row0 * (size_t)K + offs[0];
    const bf16_t* pA1 = A  + (size_t)row0 * (size_t)K + offs[1];
    const bf16_t* pB0 = Bt + (size_t)col0 * (size_t)K + offs[0];
    const bf16_t* pB1 = Bt + (size_t)col0 * (size_t)K + offs[1];

    // ---- fragment read addressing (elements), same XOR involution ----------
    const int xch  = ((lane >> 4) ^ ((lane >> 1) & 3)) << 3;
    const int aoff = (wr * 128 + (lane & 15)) * 32 + xch;
    const int boff = (wc * 64  + (lane & 15)) * 32 + xch;

    f32x4 acc[8][4];
#pragma unroll
    for (int m = 0; m < 8; ++m)
#pragma unroll
        for (int n = 0; n < 4; ++n)
            acc[m][n] = (f32x4){0.f, 0.f, 0.f, 0.f};

    const int nt = K >> 5;            // K-tiles of 32, nt >= 4

#define STAGE(t_, c_) do {                                                    \
    const size_t kk_ = (size_t)(t_) * 32;                                     \
    gload_lds16(pA0 + kk_, &lsA[c_][ldsOff0]);                                \
    gload_lds16(pA1 + kk_, &lsA[c_][ldsOff1]);                                \
    gload_lds16(pB0 + kk_, &lsB[c_][ldsOff0]);                                \
    gload_lds16(pB1 + kk_, &lsB[c_][ldsOff1]);                                \
} while (0)

    // ---- prologue: stage tiles 0,1,2; tile 0 complete ----------------------
    STAGE(0, 0); STAGE(1, 1); STAGE(2, 2);
    asm volatile("s_waitcnt vmcnt(8)" ::: "memory");   // tile 0's 4 loads done
    __builtin_amdgcn_s_barrier();
    __builtin_amdgcn_sched_barrier(0);

    int c = 0;
    for (int t = 0; t < nt; ++t) {
        bf16x8 a[8], b[4];
#pragma unroll
        for (int m = 0; m < 8; ++m)
            a[m] = *(const bf16x8*)&lsA[c][aoff + m * 512];
#pragma unroll
        for (int n = 0; n < 4; ++n)
            b[n] = *(const bf16x8*)&lsB[c][boff + n * 512];
        // own frags in regs before the barrier releases this buffer
        asm volatile("s_waitcnt lgkmcnt(0)" ::: "memory");
        __builtin_amdgcn_sched_barrier(0);
        __builtin_amdgcn_s_barrier();     // all waves done reading buf c
        __builtin_amdgcn_sched_barrier(0);
        if (t + 3 < nt) STAGE(t + 3, c);  // overwrite freed buffer
        __builtin_amdgcn_sched_barrier(0);
        __builtin_amdgcn_s_setprio(1);
#pragma unroll
        for (int m = 0; m < 8; ++m)
#pragma unroll
            for (int n = 0; n < 4; ++n)
                acc[m][n] = __builtin_amdgcn_mfma_f32_16x16x32_bf16(
                                a[m], b[n], acc[m][n], 0, 0, 0);
        __builtin_amdgcn_s_setprio(0);
        __builtin_amdgcn_sched_barrier(0);
        // counted wait: steady state leaves tiles t+2,t+3 (8 loads) in flight
        if (t + 3 < nt) { asm volatile("s_waitcnt vmcnt(8)" ::: "memory"); }
        else            { asm volatile("s_waitcnt vmcnt(0)" ::: "memory"); }
        __builtin_amdgcn_sched_barrier(0);
        __builtin_amdgcn_s_barrier();     // tile t+1 visible to all waves
        __builtin_amdgcn_sched_barrier(0);
        c = (c == 2) ? 0 : c + 1;
    }
#undef STAGE

    // ---- epilogue: C/D layout col = lane&15, row = (lane>>4)*4 + j ----------
    // (addressing identical to r5, which passed correctness)
    const int crb = row0 + wr * 128 + ((lane >> 4) << 2);
    const int ccb = col0 + wc * 64  + (lane & 15);
#pragma unroll
    for (int n = 0; n < 4; ++n) {
        const int cc = ccb + n * 16;
        const float bv = bias[cc];
#pragma unroll
        for (int m = 0; m < 8; ++m) {
            const int rb = crb + m * 16;
#pragma unroll
            for (int j = 0; j < 4; ++j) {
                float v = acc[m][n][j] + bv;
                v = v > 0.f ? v : 0.f;
                C[(size_t)(rb + j) * N + cc] = (bf16_t)v;
            }
        }
    }
}

// ---------------------------------------------------------------------------
// r4-proven 128x256 GEMM, 2 blocks/CU — used for GEMM2 (N=512 needs the
// 768-block grid; a 256^2 grid would leave half the CUs idle).
// ---------------------------------------------------------------------------
__global__ __launch_bounds__(512, 4) void gemm_bn256_bias_relu(
    const bf16_t* __restrict__ A, const bf16_t* __restrict__ Bt,
    const float* __restrict__ bias, bf16_t* __restrict__ C,
    int M, int N, int K, long long strideA)
{
    const int e = blockIdx.z;
    A    += (size_t)e * (size_t)strideA;
    Bt   += (size_t)e * (size_t)N * (size_t)K;
    bias += (size_t)e * (size_t)N;
    C    += (size_t)e * (size_t)M * (size_t)N;

    const int gx  = gridDim.x;
    const int nwg = gx * gridDim.y;
    const int lin = blockIdx.y * gx + blockIdx.x;
    const int swz = (lin & 7) * (nwg >> 3) + (lin >> 3);
    const int row0 = (swz / gx) * 128;
    const int col0 = (swz % gx) * 256;

    __shared__ bf16_t lsA[3][128 * 32];   // 3 x 8 KB
    __shared__ bf16_t lsB[3][256 * 32];   // 3 x 16 KB   -> 72 KB total

    const int tid  = threadIdx.x;
    const int lane = tid & 63;
    const int wave = tid >> 6;        // 0..7
    const int wr   = wave >> 2;       // 0..1 : 64-row half
    const int wc   = wave & 3;        // 0..3 : 64-col quarter

    size_t offA, offB0, offB1;
    {
        int rA = tid >> 2, pA = tid & 3;
        offA = (size_t)rA * (size_t)K + (size_t)(((pA ^ (rA >> 1)) & 3) * 8);
        int r0_ = tid >> 2, p0_ = tid & 3;
        offB0 = (size_t)r0_ * (size_t)K + (size_t)(((p0_ ^ (r0_ >> 1)) & 3) * 8);
        int r1_ = (512 + tid) >> 2, p1_ = tid & 3;
        offB1 = (size_t)r1_ * (size_t)K + (size_t)(((p1_ ^ (r1_ >> 1)) & 3) * 8);
    }
    const int ldsA_off = wave * 512;
    const int ldsB0off = wave * 512;
    const int ldsB1off = 4096 + wave * 512;

    const bf16_t* gA = A  + (size_t)row0 * (size_t)K;
    const bf16_t* gB = Bt + (size_t)col0 * (size_t)K;

    const int xch  = ((lane >> 4) ^ ((lane >> 1) & 3)) << 3;
    const int aoff = (wr * 64 + (lane & 15)) * 32 + xch;
    const int boff = (wc * 64 + (lane & 15)) * 32 + xch;

    f32x4 acc[4][4];
#pragma unroll
    for (int m = 0; m < 4; ++m)
#pragma unroll
        for (int n = 0; n < 4; ++n)
            acc[m][n] = (f32x4){0.f, 0.f, 0.f, 0.f};

    const int nt = K >> 5;

#define STAGE(t_, c_) do {                                                    \
    const size_t kk_ = (size_t)(t_) * 32;                                     \
    gload_lds16(gA + kk_ + offA,  &lsA[c_][ldsA_off]);                        \
    gload_lds16(gB + kk_ + offB0, &lsB[c_][ldsB0off]);                        \
    gload_lds16(gB + kk_ + offB1, &lsB[c_][ldsB1off]);                        \
} while (0)

    STAGE(0, 0); STAGE(1, 1); STAGE(2, 2);
    asm volatile("s_waitcnt vmcnt(6)" ::: "memory");
    __builtin_amdgcn_s_barrier();
    __builtin_amdgcn_sched_barrier(0);

    int c = 0;
    for (int t = 0; t < nt; ++t) {
        bf16x8 a[4], b[4];
#pragma unroll
        for (int m = 0; m < 4; ++m)
            a[m] = *(const bf16x8*)&lsA[c][aoff + m * 512];
#pragma unroll
        for (int n = 0; n < 4; ++n)
            b[n] = *(const bf16x8*)&lsB[c][boff + n * 512];
        asm volatile("s_waitcnt lgkmcnt(0)" ::: "memory");
        __builtin_amdgcn_sched_barrier(0);
        __builtin_amdgcn_s_barrier();
        __builtin_amdgcn_sched_barrier(0);
        if (t + 3 < nt) STAGE(t + 3, c);
        __builtin_amdgcn_sched_barrier(0);
        __builtin_amdgcn_s_setprio(1);
#pragma unroll
        for (int m = 0; m < 4; ++m)
#pragma unroll
            for (int n = 0; n < 4; ++n)
                acc[m][n] = __builtin_amdgcn_mfma_f32_16x16x32_bf16(
                                a[m], b[n], acc[m][n], 0, 0, 0);
        __builtin_amdgcn_s_setprio(0);
        __builtin_amdgcn_sched_barrier(0);
        if (t + 3 < nt) { asm volatile("s_waitcnt vmcnt(6)" ::: "memory"); }
        else            { asm volatile("s_waitcnt vmcnt(0)" ::: "memory"); }
        __builtin_amdgcn_sched_barrier(0);
        __builtin_amdgcn_s_barrier();
        __builtin_amdgcn_sched_barrier(0);
        c = (c == 2) ? 0 : c + 1;
    }
#undef STAGE

    const int crb = row0 + wr * 64 + ((lane >> 4) << 2);
    const int ccb = col0 + wc * 64 + (lane & 15);
#pragma unroll
    for (int n = 0; n < 4; ++n) {
        const int cc = ccb + n * 16;
        const float bv = bias[cc];
#pragma unroll
        for (int m = 0; m < 4; ++m) {
            const int rb = crb + m * 16;
#pragma unroll
            for (int j = 0; j < 4; ++j) {
                float v = acc[m][n][j] + bv;
                v = v > 0.f ? v : 0.f;
                C[(size_t)(rb + j) * N + cc] = (bf16_t)v;
            }
        }
    }
}

// ---------------------------------------------------------------------------
// gate: logits[t,b,e] = sum_g g[t,b,g] * Wgs[t,g,e]; softmax over e (EC=4).
// g lives in h1 slice 6: row (t,b) at h1[(6*B + b)*1024 + t*512 ..].
// ---------------------------------------------------------------------------
__global__ __launch_bounds__(256) void gate_kernel(
    const bf16_t* __restrict__ h1, const float* __restrict__ Wgs,
    float* __restrict__ gate)
{
    int wid  = blockIdx.x * 4 + (threadIdx.x >> 6);   // t*B + b
    int lane = threadIdx.x & 63;
    int t = wid >> 13;                                // B_ = 8192
    int b = wid & (B_ - 1);
    const bf16_t* grow = h1 + ((size_t)(6 * B_) + b) * 1024 + t * G_;
    bf16x8 gv = *(const bf16x8*)&grow[lane * 8];
    const float* W = Wgs + (size_t)t * G_ * EC_;
    float a0 = 0.f, a1 = 0.f, a2 = 0.f, a3 = 0.f;
#pragma unroll
    for (int i = 0; i < 8; ++i) {
        float gvf = (float)gv[i];
        const float4 w = *(const float4*)&W[(size_t)(lane * 8 + i) * 4];
        a0 += gvf * w.x; a1 += gvf * w.y; a2 += gvf * w.z; a3 += gvf * w.w;
    }
#pragma unroll
    for (int off = 32; off; off >>= 1) {
        a0 += __shfl_xor(a0, off);
        a1 += __shfl_xor(a1, off);
        a2 += __shfl_xor(a2, off);
        a3 += __shfl_xor(a3, off);
    }
    if (lane == 0) {
        float m  = fmaxf(fmaxf(a0, a1), fmaxf(a2, a3));
        float e0 = expf(a0 - m), e1 = expf(a1 - m), e2 = expf(a2 - m), e3 = expf(a3 - m);
        float inv = 1.f / (e0 + e1 + e2 + e3);
        *(float4*)&gate[(size_t)wid * 4] = make_float4(e0 * inv, e1 * inv, e2 * inv, e3 * inv);
    }
}

// ---------------------------------------------------------------------------
// combine: out[t,b,o] = sum_j gate[t,b,j] * h2[IDX[t][j], b, o]
// ---------------------------------------------------------------------------
__global__ __launch_bounds__(256) void combine_kernel(
    const bf16_t* __restrict__ h2, const float* __restrict__ gate,
    float* __restrict__ out)
{
    size_t idx = (size_t)blockIdx.x * 256 + threadIdx.x;
    size_t tb  = idx >> 6;
    int    o0  = (int)(idx & 63) * 8;
    int    t   = (int)(tb >> 13);
    size_t b   = tb & (size_t)(B_ - 1);
    const float4 gv = *(const float4*)&gate[tb * 4];
    const bf16x8 v0 = *(const bf16x8*)&h2[((size_t)(2 * t)     * B_ + b) * H2_ + o0];
    const bf16x8 v1 = *(const bf16x8*)&h2[((size_t)(2 * t + 1) * B_ + b) * H2_ + o0];
    const bf16x8 v2 = *(const bf16x8*)&h2[((size_t)4           * B_ + b) * H2_ + o0];
    const bf16x8 v3 = *(const bf16x8*)&h2[((size_t)5           * B_ + b) * H2_ + o0];
    float r[8];
#pragma unroll
    for (int i = 0; i < 8; ++i)
        r[i] = gv.x * (float)v0[i] + gv.y * (float)v1[i]
             + gv.z * (float)v2[i] + gv.w * (float)v3[i];
    float4* op = (float4*)&out[tb * H2_ + o0];
    op[0] = make_float4(r[0], r[1], r[2], r[3]);
    op[1] = make_float4(r[4], r[5], r[6], r[7]);
}

// ---------------------------------------------------------------------------
extern "C" void kernel_launch(void* const* d_in, const int* in_sizes, int n_in,
                              void* d_out, int out_size, void* d_ws, size_t ws_size,
                              hipStream_t stream)
{
    const float* x   = (const float*)d_in[0];
    const float* We1 = (const float*)d_in[1];
    const float* be1 = (const float*)d_in[2];
    const float* We2 = (const float*)d_in[3];
    const float* be2 = (const float*)d_in[4];
    const float* Wg1 = (const float*)d_in[5];
    const float* bg1 = (const float*)d_in[6];
    const float* Wgs = (const float*)d_in[7];
    float* out = (float*)d_out;

    char* ws = (char*)d_ws;
    bf16_t* x_bf  = (bf16_t*)ws;  ws += (size_t)B_ * D_ * 2;             //  33.6 MB
    bf16_t* w1t   = (bf16_t*)ws;  ws += (size_t)7 * H1_ * D_ * 2;        //  29.4 MB (6 experts + gate)
    bf16_t* w2t   = (bf16_t*)ws;  ws += (size_t)E_ * H2_ * H1_ * 2;      //   6.3 MB
    bf16_t* h1    = (bf16_t*)ws;  ws += (size_t)7 * B_ * H1_ * 2;        // 117.4 MB (slice 6 = gate g)
    bf16_t* h2    = (bf16_t*)ws;  ws += (size_t)E_ * B_ * H2_ * 2;       //  50.3 MB
    float*  bias7 = (float*)ws;   ws += (size_t)7 * H1_ * 4;             //  28 KB
    float*  gate  = (float*)ws;   ws += (size_t)T_ * B_ * EC_ * 4;       //   0.3 MB

    bf16_t* wgt = w1t + (size_t)6 * H1_ * D_;   // gate weights = expert slice 6

    // 0) bias concat (d2d async, graph-capture safe)
    hipMemcpyAsync(bias7, be1, (size_t)E_ * H1_ * sizeof(float),
                   hipMemcpyDeviceToDevice, stream);
    hipMemcpyAsync(bias7 + (size_t)E_ * H1_, bg1, (size_t)T_ * G_ * sizeof(float),
                   hipMemcpyDeviceToDevice, stream);

    // 1) casts / transposes
    cast_x_kernel<<<(B_ * D_ / 8) / 256, 256, 0, stream>>>(x, x_bf, B_ * D_ / 8);
    dim3 tb(32, 8);
    transpose_cast_kernel<<<dim3(H1_ / 32, D_ / 32, E_),  tb, 0, stream>>>(We1, w1t, D_,  H1_);
    transpose_cast_kernel<<<dim3(H2_ / 32, H1_ / 32, E_), tb, 0, stream>>>(We2, w2t, H1_, H2_);
    transpose_cast_kernel<<<dim3(G_ / 32, D_ / 32, T_),   tb, 0, stream>>>(Wg1, wgt, D_,  G_);

    // 2) GEMM1 + gate folded (z = 0..5 experts, z = 6 gate), 256^2 kernel
    gemm256_s_kernel<<<dim3(H1_ / 256, B_ / 256, 7), 512, 0, stream>>>(
        x_bf, w1t, bias7, h1, B_, H1_, D_, 0LL);
    // 3) GEMM2 over experts 0..5 on the r4-proven 128x256 kernel
    gemm_bn256_bias_relu<<<dim3(H2_ / 256, B_ / 128, E_), 512, 0, stream>>>(
        h1, w2t, be2, h2, B_, H2_, H1_, (long long)B_ * H1_);

    // 4) gate softmax + final combine
    gate_kernel<<<(T_ * B_) / 4, 256, 0, stream>>>(h1, Wgs, gate);
    combine_kernel<<<((size_t)T_ * B_ * H2_ / 8) / 256, 256, 0, stream>>>(h2, gate, out);
}